// Round 1
// baseline (542.370 us; speedup 1.0000x reference)
//
#include <hip/hip_runtime.h>

#define BATCH 8
#define DM 1024
#define NS 64
#define SL 2048
#define NC 16
#define TC 128   // SL/NC

// ws layout (floats):
//  BuT: [B][SL][NS]          off 0         (1,048,576 f = 4MB)
//  CuT: [B][SL][NS]          off 1048576
//  W  : [B][SL][NS]          off 2097152   (Cu * a^((l%TC)+1))
//  E  : [B][NC][NS][DM]      off 3145728   (32MB; becomes HS in-place after prefix)
// total 44MB

// ---------------- kernel 1: Bu/Cu projections (transposed) + W ----------------
__global__ __launch_bounds__(256) void k_bucu(const float* __restrict__ u,
                                              const float* __restrict__ A,
                                              const float* __restrict__ B,
                                              const float* __restrict__ C,
                                              float* __restrict__ BuT,
                                              float* __restrict__ CuT,
                                              float* __restrict__ W)
{
    __shared__ float su[32][32];          // [d-sub][l-tile]
    const int b  = blockIdx.y;
    const int l0 = blockIdx.x * 32;
    const int t  = threadIdx.x;
    const int n  = t & 63;
    const int g  = t >> 6;                // l-group 0..3 (8 l each)
    const float an = A[n * NS + n];       // diagonal of full NxN A

    float accB[8], accC[8];
#pragma unroll
    for (int i = 0; i < 8; i++) { accB[i] = 0.f; accC[i] = 0.f; }

#pragma unroll 1
    for (int d0 = 0; d0 < DM; d0 += 32) {
        __syncthreads();
        {   // stage u[b][d0..d0+32][l0..l0+32): 1024 floats = 256 float4, 1/thread
            int r = t >> 3, f = t & 7;
            float4 v = *(const float4*)&u[((size_t)b * DM + d0 + r) * SL + l0 + f * 4];
            su[r][f * 4 + 0] = v.x; su[r][f * 4 + 1] = v.y;
            su[r][f * 4 + 2] = v.z; su[r][f * 4 + 3] = v.w;
        }
        __syncthreads();
#pragma unroll 4
        for (int dd = 0; dd < 32; dd++) {
            float bv = B[(size_t)(d0 + dd) * NS + n];
            float cv = C[(size_t)(d0 + dd) * NS + n];
#pragma unroll
            for (int i = 0; i < 8; i++) {
                float uv = su[dd][g * 8 + i];          // broadcast within wave
                accB[i] = fmaf(bv, uv, accB[i]);
                accC[i] = fmaf(cv, uv, accC[i]);
            }
        }
    }
#pragma unroll
    for (int i = 0; i < 8; i++) {
        int l = l0 + g * 8 + i;
        size_t o = ((size_t)b * SL + l) * NS + n;
        BuT[o] = accB[i];
        CuT[o] = accC[i];
        int k = (l & (TC - 1)) + 1;
        W[o] = accC[i] * __powf(an, (float)k);
    }
}

// ---------------- kernel 2: per-chunk local scan (zero init) ----------------
__global__ __launch_bounds__(64) void k_scan(const float* __restrict__ u,
                                             const float* __restrict__ A,
                                             const float* __restrict__ BuT,
                                             const float* __restrict__ CuT,
                                             float* __restrict__ E,
                                             float* __restrict__ y)
{
    const int dt   = blockIdx.x;          // 0..15
    const int c    = blockIdx.y;          // 0..NC-1
    const int b    = blockIdx.z;
    const int lane = threadIdx.x;         // 0..63
    const int d    = dt * 64 + lane;
    const int l0   = c * TC;

    float a[64];
#pragma unroll
    for (int j = 0; j < 64; j++) a[j] = A[j * NS + j];   // wave-uniform

    float h[64];
#pragma unroll
    for (int j = 0; j < 64; j++) h[j] = 0.f;

    const float* uptr = u + ((size_t)b * DM + d) * SL + l0;
    float*       yptr = y + ((size_t)b * DM + d) * SL + l0;
    const float* buBase = BuT + (size_t)(b * SL + l0) * NS;
    const float* cuBase = CuT + (size_t)(b * SL + l0) * NS;

#pragma unroll 1
    for (int lq = 0; lq < TC / 4; lq++) {
        float4 u4 = *(const float4*)(uptr + lq * 4);
        float ua[4] = { u4.x, u4.y, u4.z, u4.w };
        float yr[4];
#pragma unroll
        for (int i = 0; i < 4; i++) {
            int l = lq * 4 + i;
            const float* bu = buBase + (size_t)l * NS;   // wave-uniform -> s_load
            const float* cu = cuBase + (size_t)l * NS;
            float uv = ua[i];
            float y0 = 0.f, y1 = 0.f;
#pragma unroll
            for (int j = 0; j < 64; j += 2) {
                h[j]     = fmaf(a[j],     h[j],     bu[j]     * uv);
                y0       = fmaf(cu[j],    h[j],     y0);
                h[j + 1] = fmaf(a[j + 1], h[j + 1], bu[j + 1] * uv);
                y1       = fmaf(cu[j + 1], h[j + 1], y1);
            }
            yr[i] = y0 + y1;
        }
        float4 y4 = { yr[0], yr[1], yr[2], yr[3] };
        *(float4*)(yptr + lq * 4) = y4;
    }
    // chunk-local end state
#pragma unroll
    for (int j = 0; j < 64; j++)
        E[(((size_t)b * NC + c) * NS + j) * DM + d] = h[j];
}

// ---------------- kernel 3: prefix over chunks (E -> HS, in place) ----------------
__global__ __launch_bounds__(256) void k_prefix(const float* __restrict__ A,
                                                float* __restrict__ E)
{
    int g = blockIdx.x * 256 + threadIdx.x;       // 0 .. B*NS*DM-1
    int d = g & (DM - 1);
    int n = (g >> 10) & (NS - 1);
    int b = g >> 16;
    float an = A[n * NS + n];
    float aT = __powf(an, (float)TC);
    float hs = 0.f;
#pragma unroll 1
    for (int c = 0; c < NC; c++) {
        size_t o = (((size_t)b * NC + c) * NS + n) * DM + d;
        float e = E[o];
        E[o] = hs;                                 // state at START of chunk c
        hs = fmaf(aT, hs, e);
    }
}

// ---------------- kernel 4: cross-chunk correction ----------------
__global__ __launch_bounds__(64) void k_corr(const float* __restrict__ HS,
                                             const float* __restrict__ W,
                                             float* __restrict__ y)
{
    const int dt   = blockIdx.x;
    const int c    = blockIdx.y + 1;              // chunk 0 has zero start state
    const int b    = blockIdx.z;
    const int lane = threadIdx.x;
    const int d    = dt * 64 + lane;
    const int l0   = c * TC;

    float hs[64];
#pragma unroll
    for (int j = 0; j < 64; j++)
        hs[j] = HS[(((size_t)b * NC + c) * NS + j) * DM + d];

    float* yptr = y + ((size_t)b * DM + d) * SL + l0;
    const float* wBase = W + (size_t)(b * SL + l0) * NS;

#pragma unroll 1
    for (int lq = 0; lq < TC / 4; lq++) {
        float4 y4 = *(float4*)(yptr + lq * 4);
        float yr[4];
#pragma unroll
        for (int i = 0; i < 4; i++) {
            const float* w = wBase + (size_t)(lq * 4 + i) * NS;   // wave-uniform
            float y0 = 0.f, y1 = 0.f;
#pragma unroll
            for (int j = 0; j < 64; j += 2) {
                y0 = fmaf(w[j],     hs[j],     y0);
                y1 = fmaf(w[j + 1], hs[j + 1], y1);
            }
            yr[i] = y0 + y1;
        }
        y4.x += yr[0]; y4.y += yr[1]; y4.z += yr[2]; y4.w += yr[3];
        *(float4*)(yptr + lq * 4) = y4;
    }
}

extern "C" void kernel_launch(void* const* d_in, const int* in_sizes, int n_in,
                              void* d_out, int out_size, void* d_ws, size_t ws_size,
                              hipStream_t stream) {
    const float* u = (const float*)d_in[1];
    const float* A = (const float*)d_in[2];
    const float* B = (const float*)d_in[3];
    const float* C = (const float*)d_in[4];
    float* y = (float*)d_out;

    float* ws  = (float*)d_ws;
    float* BuT = ws;
    float* CuT = ws + 1048576;
    float* W   = ws + 2097152;
    float* E   = ws + 3145728;

    k_bucu<<<dim3(SL / 32, BATCH), 256, 0, stream>>>(u, A, B, C, BuT, CuT, W);
    k_scan<<<dim3(DM / 64, NC, BATCH), 64, 0, stream>>>(u, A, BuT, CuT, E, y);
    k_prefix<<<dim3(BATCH * NS * DM / 256), 256, 0, stream>>>(A, E);
    k_corr<<<dim3(DM / 64, NC - 1, BATCH), 64, 0, stream>>>(E, W, y);
}

// Round 2
// 515.606 us; speedup vs baseline: 1.0519x; 1.0519x over previous
//
#include <hip/hip_runtime.h>
#include <hip/hip_bf16.h>

#define BATCH 8
#define DM 1024
#define NS 64
#define SL 2048
#define NC 32
#define TC 64   // SL/NC

// ws layout:
//  BuT: [B][SL][NS]  f32  off 0         (4MB)
//  CuT: [B][SL][NS]  f32  off 1048576   (4MB)
//  W  : [B][SL][NS]  f32  off 2097152   (4MB)   Cu * a^((l%TC)+1)
//  E  : [B][NC][NS][DM] bf16 at float-off 3145728 (32MB; becomes HS in place)
// total 44MB (same footprint as the proven R1 layout)

// ---------------- kernel 1: Bu/Cu projections (transposed) + W ----------------
__global__ __launch_bounds__(256) void k_bucu(const float* __restrict__ u,
                                              const float* __restrict__ A,
                                              const float* __restrict__ B,
                                              const float* __restrict__ C,
                                              float* __restrict__ BuT,
                                              float* __restrict__ CuT,
                                              float* __restrict__ W)
{
    __shared__ float su[32][32];          // [d-sub][l-tile]
    const int b  = blockIdx.y;
    const int l0 = blockIdx.x * 32;
    const int t  = threadIdx.x;
    const int n  = t & 63;
    const int g  = t >> 6;                // l-group 0..3 (8 l each)
    const float an = A[n * NS + n];       // diagonal of full NxN A

    float accB[8], accC[8];
#pragma unroll
    for (int i = 0; i < 8; i++) { accB[i] = 0.f; accC[i] = 0.f; }

#pragma unroll 1
    for (int d0 = 0; d0 < DM; d0 += 32) {
        __syncthreads();
        {   // stage u[b][d0..d0+32][l0..l0+32): 1024 floats
            int r = t >> 3, f = t & 7;
            float4 v = *(const float4*)&u[((size_t)b * DM + d0 + r) * SL + l0 + f * 4];
            su[r][f * 4 + 0] = v.x; su[r][f * 4 + 1] = v.y;
            su[r][f * 4 + 2] = v.z; su[r][f * 4 + 3] = v.w;
        }
        __syncthreads();
#pragma unroll 4
        for (int dd = 0; dd < 32; dd++) {
            float bv = B[(size_t)(d0 + dd) * NS + n];
            float cv = C[(size_t)(d0 + dd) * NS + n];
#pragma unroll
            for (int i = 0; i < 8; i++) {
                float uv = su[dd][g * 8 + i];
                accB[i] = fmaf(bv, uv, accB[i]);
                accC[i] = fmaf(cv, uv, accC[i]);
            }
        }
    }
#pragma unroll
    for (int i = 0; i < 8; i++) {
        int l = l0 + g * 8 + i;
        size_t o = ((size_t)b * SL + l) * NS + n;
        BuT[o] = accB[i];
        CuT[o] = accC[i];
        int k = (l & (TC - 1)) + 1;
        W[o] = accC[i] * __powf(an, (float)k);
    }
}

// ---------------- kernel 2: per-chunk local scan (zero init) ----------------
__global__ __launch_bounds__(256) void k_scan(const float* __restrict__ u,
                                              const float* __restrict__ A,
                                              const float* __restrict__ BuT,
                                              const float* __restrict__ CuT,
                                              __hip_bfloat16* __restrict__ E,
                                              float* __restrict__ y)
{
    const int c    = blockIdx.y;          // 0..NC-1
    const int b    = blockIdx.z;
    const int d    = blockIdx.x * 256 + threadIdx.x;
    const int l0   = c * TC;

    float a[64];
#pragma unroll
    for (int j = 0; j < 64; j++) a[j] = A[j * NS + j];   // block-uniform -> SGPR

    float h[64];
#pragma unroll
    for (int j = 0; j < 64; j++) h[j] = 0.f;

    const float* uptr = u + ((size_t)b * DM + d) * SL + l0;
    float*       yptr = y + ((size_t)b * DM + d) * SL + l0;
    const float* buBase = BuT + (size_t)(b * SL + l0) * NS;
    const float* cuBase = CuT + (size_t)(b * SL + l0) * NS;

#pragma unroll 1
    for (int lq = 0; lq < TC / 4; lq++) {
        float4 u4 = *(const float4*)(uptr + lq * 4);
        float ua[4] = { u4.x, u4.y, u4.z, u4.w };
        float yr[4];
#pragma unroll
        for (int i = 0; i < 4; i++) {
            int l = lq * 4 + i;
            const float* bu = buBase + (size_t)l * NS;   // block-uniform -> s_load
            const float* cu = cuBase + (size_t)l * NS;
            float uv = ua[i];
            float y0 = 0.f, y1 = 0.f;
#pragma unroll
            for (int j = 0; j < 64; j += 2) {
                h[j]     = fmaf(a[j],     h[j],     bu[j]     * uv);
                y0       = fmaf(cu[j],    h[j],     y0);
                h[j + 1] = fmaf(a[j + 1], h[j + 1], bu[j + 1] * uv);
                y1       = fmaf(cu[j + 1], h[j + 1], y1);
            }
            yr[i] = y0 + y1;
        }
        float4 y4 = { yr[0], yr[1], yr[2], yr[3] };
        *(float4*)(yptr + lq * 4) = y4;
    }
    // chunk-local end state (bf16)
#pragma unroll
    for (int j = 0; j < 64; j++)
        E[(((size_t)b * NC + c) * NS + j) * DM + d] = __float2bfloat16(h[j]);
}

// ---------------- kernel 3: prefix over chunks (E -> HS, in place) ----------------
__global__ __launch_bounds__(256) void k_prefix(const float* __restrict__ A,
                                                __hip_bfloat16* __restrict__ E)
{
    int g = blockIdx.x * 256 + threadIdx.x;       // 0 .. B*NS*DM-1
    int d = g & (DM - 1);
    int n = (g >> 10) & (NS - 1);
    int b = g >> 16;
    float an = A[n * NS + n];
    float aT = __powf(an, (float)TC);
    float hs = 0.f;
#pragma unroll 1
    for (int c = 0; c < NC; c++) {
        size_t o = (((size_t)b * NC + c) * NS + n) * DM + d;
        float e = __bfloat162float(E[o]);
        E[o] = __float2bfloat16(hs);               // state at START of chunk c
        hs = fmaf(aT, hs, e);
    }
}

// ---------------- kernel 4: cross-chunk correction ----------------
__global__ __launch_bounds__(256) void k_corr(const __hip_bfloat16* __restrict__ HS,
                                              const float* __restrict__ W,
                                              float* __restrict__ y)
{
    const int c    = blockIdx.y + 1;              // chunk 0 has zero start state
    const int b    = blockIdx.z;
    const int d    = blockIdx.x * 256 + threadIdx.x;
    const int l0   = c * TC;

    float hs[64];
#pragma unroll
    for (int j = 0; j < 64; j++)
        hs[j] = __bfloat162float(HS[(((size_t)b * NC + c) * NS + j) * DM + d]);

    float* yptr = y + ((size_t)b * DM + d) * SL + l0;
    const float* wBase = W + (size_t)(b * SL + l0) * NS;

#pragma unroll 1
    for (int lq = 0; lq < TC / 4; lq++) {
        float4 y4 = *(float4*)(yptr + lq * 4);
        float yr[4];
#pragma unroll
        for (int i = 0; i < 4; i++) {
            const float* w = wBase + (size_t)(lq * 4 + i) * NS;   // block-uniform
            float y0 = 0.f, y1 = 0.f;
#pragma unroll
            for (int j = 0; j < 64; j += 2) {
                y0 = fmaf(w[j],     hs[j],     y0);
                y1 = fmaf(w[j + 1], hs[j + 1], y1);
            }
            yr[i] = y0 + y1;
        }
        y4.x += yr[0]; y4.y += yr[1]; y4.z += yr[2]; y4.w += yr[3];
        *(float4*)(yptr + lq * 4) = y4;
    }
}

extern "C" void kernel_launch(void* const* d_in, const int* in_sizes, int n_in,
                              void* d_out, int out_size, void* d_ws, size_t ws_size,
                              hipStream_t stream) {
    const float* u = (const float*)d_in[1];
    const float* A = (const float*)d_in[2];
    const float* B = (const float*)d_in[3];
    const float* C = (const float*)d_in[4];
    float* y = (float*)d_out;

    float* ws  = (float*)d_ws;
    float* BuT = ws;
    float* CuT = ws + 1048576;
    float* W   = ws + 2097152;
    __hip_bfloat16* E = (__hip_bfloat16*)(ws + 3145728);

    k_bucu<<<dim3(SL / 32, BATCH), 256, 0, stream>>>(u, A, B, C, BuT, CuT, W);
    k_scan<<<dim3(DM / 256, NC, BATCH), 256, 0, stream>>>(u, A, BuT, CuT, E, y);
    k_prefix<<<dim3(BATCH * NS * DM / 256), 256, 0, stream>>>(A, E);
    k_corr<<<dim3(DM / 256, NC - 1, BATCH), 256, 0, stream>>>(E, W, y);
}

// Round 3
// 403.507 us; speedup vs baseline: 1.3441x; 1.2778x over previous
//
#include <hip/hip_runtime.h>
#include <hip/hip_bf16.h>

#define BATCH 8
#define DM 1024
#define NS 64
#define SL 2048
#define NC 32
#define TC 64   // SL/NC

// ws layout (floats):
//  BuT: [B][SL][NS]  f32  off 0         (4MB)
//  CuT: [B][SL][NS]  f32  off 1048576   (4MB)
//  W  : [B][SL][NS]  f32  off 2097152   (4MB)   Cu * a^((l%TC)+1)
//  E  : [B][NC][NS][DM] bf16 at float-off 3145728 (32MB; becomes HS in place)
// total 44MB (proven footprint)

// ---------------- kernel 1: Bu/Cu projections (transposed) + W ----------------
// grid (SL/16, BATCH), block 256. Thread (n = t&63, g = t>>6) covers 4 l each.
__global__ __launch_bounds__(256) void k_bucu(const float* __restrict__ u,
                                              const float* __restrict__ A,
                                              const float* __restrict__ B,
                                              const float* __restrict__ C,
                                              float* __restrict__ BuT,
                                              float* __restrict__ CuT,
                                              float* __restrict__ W)
{
    __shared__ float su[32][16];   // [d-sub][l-tile]  2KB
    __shared__ float sB[32][64];   // [d-sub][n]       8KB
    __shared__ float sC[32][64];   //                  8KB
    const int b  = blockIdx.y;
    const int l0 = blockIdx.x * 16;
    const int t  = threadIdx.x;
    const int n  = t & 63;
    const int g  = t >> 6;                // 0..3, 4 l each

    float accB[4] = {0.f, 0.f, 0.f, 0.f};
    float accC[4] = {0.f, 0.f, 0.f, 0.f};

#pragma unroll 1
    for (int d0 = 0; d0 < DM; d0 += 32) {
        __syncthreads();
        {   // stage u[b][d0+r][l0 + f..f+1]: 512 floats
            int r = t >> 3, f = (t & 7) * 2;
            float2 v = *(const float2*)&u[((size_t)b * DM + d0 + r) * SL + l0 + f];
            su[r][f] = v.x; su[r][f + 1] = v.y;
        }
        {   // stage B,C rows d0..d0+31 (2048 floats each): 2 float4 per thread per array
            int r = t >> 3, q = (t & 7) * 8;
            float4 v0 = *(const float4*)&B[(size_t)(d0 + r) * NS + q];
            float4 v1 = *(const float4*)&B[(size_t)(d0 + r) * NS + q + 4];
            sB[r][q + 0] = v0.x; sB[r][q + 1] = v0.y; sB[r][q + 2] = v0.z; sB[r][q + 3] = v0.w;
            sB[r][q + 4] = v1.x; sB[r][q + 5] = v1.y; sB[r][q + 6] = v1.z; sB[r][q + 7] = v1.w;
            float4 w0 = *(const float4*)&C[(size_t)(d0 + r) * NS + q];
            float4 w1 = *(const float4*)&C[(size_t)(d0 + r) * NS + q + 4];
            sC[r][q + 0] = w0.x; sC[r][q + 1] = w0.y; sC[r][q + 2] = w0.z; sC[r][q + 3] = w0.w;
            sC[r][q + 4] = w1.x; sC[r][q + 5] = w1.y; sC[r][q + 6] = w1.z; sC[r][q + 7] = w1.w;
        }
        __syncthreads();
#pragma unroll 8
        for (int dd = 0; dd < 32; dd++) {
            float bv = sB[dd][n];               // stride-1 across lanes: conflict-free
            float cv = sC[dd][n];
#pragma unroll
            for (int i = 0; i < 4; i++) {
                float uv = su[dd][g * 4 + i];   // wave-uniform broadcast
                accB[i] = fmaf(bv, uv, accB[i]);
                accC[i] = fmaf(cv, uv, accC[i]);
            }
        }
    }
    const float an = A[n * NS + n];
#pragma unroll
    for (int i = 0; i < 4; i++) {
        int l = l0 + g * 4 + i;
        size_t o = ((size_t)b * SL + l) * NS + n;
        BuT[o] = accB[i];
        CuT[o] = accC[i];
        int k = (l & (TC - 1)) + 1;
        W[o] = accC[i] * __powf(an, (float)k);
    }
}

// ---------------- kernel 2: per-chunk local scan (zero init) ----------------
// grid (DM/256, NC, BATCH), block 256.
__global__ __launch_bounds__(256) void k_scan(const float* __restrict__ u,
                                              const float* __restrict__ A,
                                              const float* __restrict__ BuT,
                                              const float* __restrict__ CuT,
                                              __hip_bfloat16* __restrict__ E,
                                              float* __restrict__ y)
{
    __shared__ float sBu[TC][NS];   // 16KB
    __shared__ float sCu[TC][NS];   // 16KB
    const int c  = blockIdx.y;
    const int b  = blockIdx.z;
    const int t  = threadIdx.x;
    const int d  = blockIdx.x * 256 + t;
    const int l0 = c * TC;

    {   // stage chunk coefficients: 4096 floats each, 4 float4 per thread per array
        const float* srcB = BuT + (size_t)(b * SL + l0) * NS;
        const float* srcC = CuT + (size_t)(b * SL + l0) * NS;
        float* dB = &sBu[0][0];
        float* dC = &sCu[0][0];
#pragma unroll
        for (int k = 0; k < 4; k++) {
            int e = (k * 256 + t) * 4;
            *(float4*)&dB[e] = *(const float4*)&srcB[e];
            *(float4*)&dC[e] = *(const float4*)&srcC[e];
        }
    }

    float a[64];
#pragma unroll
    for (int j = 0; j < 64; j++) a[j] = A[j * NS + j];   // uniform -> SGPRs

    float h[64];
#pragma unroll
    for (int j = 0; j < 64; j++) h[j] = 0.f;

    __syncthreads();

    const float* uptr = u + ((size_t)b * DM + d) * SL + l0;
    float*       yptr = y + ((size_t)b * DM + d) * SL + l0;

#pragma unroll 1
    for (int lq = 0; lq < TC / 4; lq++) {
        float4 u4 = *(const float4*)(uptr + lq * 4);
        float ua[4] = { u4.x, u4.y, u4.z, u4.w };
        float yr[4];
#pragma unroll
        for (int i = 0; i < 4; i++) {
            int l = lq * 4 + i;
            float uv = ua[i];
            float y0 = 0.f, y1 = 0.f;
#pragma unroll
            for (int j = 0; j < 64; j += 4) {
                float4 bu4 = *(const float4*)&sBu[l][j];   // uniform addr: broadcast
                float4 cu4 = *(const float4*)&sCu[l][j];
                h[j]     = fmaf(a[j],     h[j],     bu4.x * uv);
                y0       = fmaf(cu4.x,   h[j],     y0);
                h[j + 1] = fmaf(a[j + 1], h[j + 1], bu4.y * uv);
                y1       = fmaf(cu4.y,   h[j + 1], y1);
                h[j + 2] = fmaf(a[j + 2], h[j + 2], bu4.z * uv);
                y0       = fmaf(cu4.z,   h[j + 2], y0);
                h[j + 3] = fmaf(a[j + 3], h[j + 3], bu4.w * uv);
                y1       = fmaf(cu4.w,   h[j + 3], y1);
            }
            yr[i] = y0 + y1;
        }
        float4 y4 = { yr[0], yr[1], yr[2], yr[3] };
        *(float4*)(yptr + lq * 4) = y4;
    }
    // chunk-local end state (bf16)
#pragma unroll
    for (int j = 0; j < 64; j++)
        E[(((size_t)b * NC + c) * NS + j) * DM + d] = __float2bfloat16(h[j]);
}

// ---------------- kernel 3: prefix over chunks (E -> HS, in place) ----------------
__global__ __launch_bounds__(256) void k_prefix(const float* __restrict__ A,
                                                __hip_bfloat16* __restrict__ E)
{
    int g = blockIdx.x * 256 + threadIdx.x;       // 0 .. B*NS*DM-1
    int d = g & (DM - 1);
    int n = (g >> 10) & (NS - 1);
    int b = g >> 16;
    float an = A[n * NS + n];
    float aT = __powf(an, (float)TC);
    float hs = 0.f;
#pragma unroll 1
    for (int c = 0; c < NC; c++) {
        size_t o = (((size_t)b * NC + c) * NS + n) * DM + d;
        float e = __bfloat162float(E[o]);
        E[o] = __float2bfloat16(hs);               // state at START of chunk c
        hs = fmaf(aT, hs, e);
    }
}

// ---------------- kernel 4: cross-chunk correction ----------------
// grid (DM/256, NC-1, BATCH), block 256.
__global__ __launch_bounds__(256) void k_corr(const __hip_bfloat16* __restrict__ HS,
                                              const float* __restrict__ W,
                                              float* __restrict__ y)
{
    __shared__ float sW[TC][NS];    // 16KB
    const int c  = blockIdx.y + 1;                // chunk 0 has zero start state
    const int b  = blockIdx.z;
    const int t  = threadIdx.x;
    const int d  = blockIdx.x * 256 + t;
    const int l0 = c * TC;

    {   // stage W chunk: 4096 floats
        const float* src = W + (size_t)(b * SL + l0) * NS;
        float* dW = &sW[0][0];
#pragma unroll
        for (int k = 0; k < 4; k++) {
            int e = (k * 256 + t) * 4;
            *(float4*)&dW[e] = *(const float4*)&src[e];
        }
    }

    float hs[64];
#pragma unroll
    for (int j = 0; j < 64; j++)
        hs[j] = __bfloat162float(HS[(((size_t)b * NC + c) * NS + j) * DM + d]);

    __syncthreads();

    float* yptr = y + ((size_t)b * DM + d) * SL + l0;

#pragma unroll 1
    for (int lq = 0; lq < TC / 4; lq++) {
        float4 y4 = *(float4*)(yptr + lq * 4);
        float yr[4];
#pragma unroll
        for (int i = 0; i < 4; i++) {
            int l = lq * 4 + i;
            float y0 = 0.f, y1 = 0.f;
#pragma unroll
            for (int j = 0; j < 64; j += 4) {
                float4 w4 = *(const float4*)&sW[l][j];   // uniform addr: broadcast
                y0 = fmaf(w4.x, hs[j],     y0);
                y1 = fmaf(w4.y, hs[j + 1], y1);
                y0 = fmaf(w4.z, hs[j + 2], y0);
                y1 = fmaf(w4.w, hs[j + 3], y1);
            }
            yr[i] = y0 + y1;
        }
        y4.x += yr[0]; y4.y += yr[1]; y4.z += yr[2]; y4.w += yr[3];
        *(float4*)(yptr + lq * 4) = y4;
    }
}

extern "C" void kernel_launch(void* const* d_in, const int* in_sizes, int n_in,
                              void* d_out, int out_size, void* d_ws, size_t ws_size,
                              hipStream_t stream) {
    const float* u = (const float*)d_in[1];
    const float* A = (const float*)d_in[2];
    const float* B = (const float*)d_in[3];
    const float* C = (const float*)d_in[4];
    float* y = (float*)d_out;

    float* ws  = (float*)d_ws;
    float* BuT = ws;
    float* CuT = ws + 1048576;
    float* W   = ws + 2097152;
    __hip_bfloat16* E = (__hip_bfloat16*)(ws + 3145728);

    k_bucu<<<dim3(SL / 16, BATCH), 256, 0, stream>>>(u, A, B, C, BuT, CuT, W);
    k_scan<<<dim3(DM / 256, NC, BATCH), 256, 0, stream>>>(u, A, BuT, CuT, E, y);
    k_prefix<<<dim3(BATCH * NS * DM / 256), 256, 0, stream>>>(A, E);
    k_corr<<<dim3(DM / 256, NC - 1, BATCH), 256, 0, stream>>>(E, W, y);
}